// Round 11
// baseline (507.769 us; speedup 1.0000x reference)
//
#include <hip/hip_runtime.h>
#include <math.h>

// ---------------------------------------------------------------------------
// Round 11: chain fusion via LDS-bounce (validated in r10's embed_fused).
//   embed_c_rw : child embed (2 layers) + RW_c pass in one kernel
//   conv_fused : h_c (stage1, regs) -> LDS bounce -> LW_c = h@Wx + cx
//   conv_head  : h_p (stage1, regs) -> LDS bounce -> relu(h@Wh+bh) . w2 -> out
// Deletes 3 GEMM dispatches + ~104MB of intermediate round trips.
// CSR sort, gathers, featconv2, embed_fused (pivot) unchanged from r10.
// ---------------------------------------------------------------------------

typedef unsigned short u16;
typedef __attribute__((ext_vector_type(8))) short s8v;   // 8 bf16 = 4 VGPR
typedef __attribute__((ext_vector_type(4))) float f4v;   // MFMA C/D frag

__device__ __forceinline__ float bf2f(u16 u) {
    unsigned x = ((unsigned)u) << 16;
    return __builtin_bit_cast(float, x);
}
__device__ __forceinline__ u16 f2bf(float f) {
    unsigned x = __builtin_bit_cast(unsigned, f);
    unsigned r = x + 0x7fffu + ((x >> 16) & 1u);
    return (u16)(r >> 16);
}
__device__ __forceinline__ unsigned pk2(float a, float b) {
    return (unsigned)f2bf(a) | ((unsigned)f2bf(b) << 16);
}
__device__ __forceinline__ void unpack8(uint4 u, float* f) {
    f[0] = bf2f((u16)(u.x & 0xffff)); f[1] = bf2f((u16)(u.x >> 16));
    f[2] = bf2f((u16)(u.y & 0xffff)); f[3] = bf2f((u16)(u.y >> 16));
    f[4] = bf2f((u16)(u.z & 0xffff)); f[5] = bf2f((u16)(u.z >> 16));
    f[6] = bf2f((u16)(u.w & 0xffff)); f[7] = bf2f((u16)(u.w >> 16));
}

// ---- small fp32 128x128 matmuls for folded weights ----
struct SmEnt { const float* A; const float* B; const float* s; };
struct SmPack { SmEnt e[4]; };

__global__ __launch_bounds__(256) void smallmm(SmPack p, float* __restrict__ out)
{
    int t = blockIdx.x * 256 + threadIdx.x;
    int m = t >> 14;
    int o = t & 16383;
    int i = o >> 7, j = o & 127;
    SmEnt en = p.e[m];
    float acc = 0.f;
#pragma unroll 4
    for (int k = 0; k < 128; ++k) acc += en.A[i * 128 + k] * en.B[k * 128 + j];
    if (en.s) acc *= *en.s;
    out[(size_t)m * 16384 + o] = acc;
}

__global__ void vecpre(
    const float* vc_bf, const float* vc_wo1, const float* vc_sp,
    const float* cv_bf, const float* cv_wo1, const float* cv_sp,
    const float* vc_bo2, const float* cv_wr,
    const float* cv_bo2, const float* out_w1, const float* out_b1,
    float* __restrict__ vout)
{
    int j = threadIdx.x;
    if (j >= 128) return;
    float a0 = 0.f, a1 = 0.f, a2 = 0.f, a3 = 0.f;
    for (int k = 0; k < 128; ++k) {
        a0 += vc_bf[k] * vc_wo1[k * 128 + j];
        a1 += cv_bf[k] * cv_wo1[k * 128 + j];
        a2 += vc_bo2[k] * cv_wr[k * 128 + j];
        a3 += cv_bo2[k] * out_w1[k * 128 + j];
    }
    vout[j] = a0 * (*vc_sp);
    vout[128 + j] = a1 * (*cv_sp);
    vout[256 + j] = a2;
    vout[384 + j] = a3 + out_b1[j];
}

// ---- weight conversion: fp32 [Ksrc][128] -> bf16 WT[col*Kdst + k], pad k ----
struct WEnt { const float* src; int Ksrc; int Kdst; };
struct WPack { WEnt e[14]; };

__global__ __launch_bounds__(256) void wconvert(WPack p, u16* __restrict__ wt)
{
    int t = blockIdx.x * 256 + threadIdx.x;
    int m = t >> 15;
    int i = t & 32767;
    WEnt en = p.e[m];
    if (i >= (en.Kdst << 7)) return;
    int k = i >> 7, col = i & 127;
    float v = (k < en.Ksrc) ? en.src[k * 128 + col] : 0.f;
    wt[(size_t)m * 32768 + (size_t)col * en.Kdst + k] = f2bf(v);
}

// ---- feature conversion (both tables): fp32 [M,F]+prenorm -> bf16 [M,96] ----
__global__ __launch_bounds__(256) void featconv2(
    const float* __restrict__ pv, const float* __restrict__ ch,
    const float* __restrict__ psh, const float* __restrict__ psc,
    const float* __restrict__ csh, const float* __restrict__ csc,
    u16* __restrict__ y, long NPr, long total, int F)
{
    for (long i = (long)blockIdx.x * 256 + threadIdx.x; i < total;
         i += (long)gridDim.x * 256) {
        int cc = (int)(i % 96);
        long r = i / 96;
        const float *x, *sh, *sc;
        long row;
        if (r < NPr) { x = pv; sh = psh; sc = psc; row = r; }
        else { x = ch; sh = csh; sc = csc; row = r - NPr; }
        float v = 0.f;
        if (cc < F) {
            v = x[row * F + cc];
            v = (v + sh[cc]) * sc[cc];
        }
        y[i] = f2bf(v);
    }
}

// ---- fused two-layer embed MLP (pivot) ----
__global__ __launch_bounds__(256) void embed_fused(
    const u16* __restrict__ A, const u16* __restrict__ W1,
    const float* __restrict__ b1, const u16* __restrict__ W2,
    const float* __restrict__ b2, u16* __restrict__ out, int M)
{
    __shared__ u16 w2s[128 * 136];
    __shared__ u16 tile[4][16 * 136];
    const int tid = threadIdx.x;
    for (int i = tid; i < 8192; i += 256) {
        int col = i >> 6, kp = (i & 63) << 1;
        *(unsigned*)&w2s[col * 136 + kp] = *(const unsigned*)&W2[(size_t)col * 128 + kp];
    }
    __syncthreads();

    const int lane = tid & 63;
    const int c = lane & 15;
    const int kg = lane >> 4;
    const int wv = tid >> 6;
    const int wid = blockIdx.x * 4 + wv;
    const int ws = gridDim.x * 4;
    const int items = M >> 4;
    u16* tl = tile[wv];

    const u16* wbase = W1 + (size_t)c * 96 + kg * 8;
    s8v bp1[3][8];
#pragma unroll
    for (int ks = 0; ks < 3; ++ks)
#pragma unroll
        for (int nt = 0; nt < 8; ++nt)
            bp1[ks][nt] = *(const s8v*)(wbase + ((size_t)nt * 16) * 96 + ks * 32);

    f4v b1q[8], b2q[8];
#pragma unroll
    for (int nt = 0; nt < 8; ++nt) {
        b1q[nt] = *(const f4v*)(b1 + nt * 16 + kg * 4);
        b2q[nt] = *(const f4v*)(b2 + nt * 16 + kg * 4);
    }

    for (int item = wid; item < items; item += ws) {
        const int r0 = item << 4;
        const u16* ap = A + (size_t)(r0 + c) * 96 + kg * 8;
        s8v a[3];
#pragma unroll
        for (int ks = 0; ks < 3; ++ks) a[ks] = *(const s8v*)(ap + ks * 32);

        f4v acc[8];
#pragma unroll
        for (int nt = 0; nt < 8; ++nt) acc[nt] = (f4v){0.f, 0.f, 0.f, 0.f};
#pragma unroll
        for (int ks = 0; ks < 3; ++ks)
#pragma unroll
            for (int nt = 0; nt < 8; ++nt)
                acc[nt] = __builtin_amdgcn_mfma_f32_16x16x32_bf16(bp1[ks][nt], a[ks], acc[nt], 0, 0, 0);

#pragma unroll
        for (int nt = 0; nt < 8; ++nt) {
            uint2 pkv;
            pkv.x = pk2(fmaxf(acc[nt][0] + b1q[nt][0], 0.f), fmaxf(acc[nt][1] + b1q[nt][1], 0.f));
            pkv.y = pk2(fmaxf(acc[nt][2] + b1q[nt][2], 0.f), fmaxf(acc[nt][3] + b1q[nt][3], 0.f));
            *(uint2*)&tl[c * 136 + nt * 16 + kg * 4] = pkv;
        }

        s8v a2[4];
#pragma unroll
        for (int ks = 0; ks < 4; ++ks)
            a2[ks] = *(const s8v*)&tl[c * 136 + ks * 32 + kg * 8];

        f4v acc2[8];
#pragma unroll
        for (int nt = 0; nt < 8; ++nt) acc2[nt] = (f4v){0.f, 0.f, 0.f, 0.f};
#pragma unroll
        for (int ks = 0; ks < 4; ++ks)
#pragma unroll
            for (int nt = 0; nt < 8; ++nt) {
                s8v b = *(const s8v*)&w2s[(size_t)(nt * 16 + c) * 136 + ks * 32 + kg * 8];
                acc2[nt] = __builtin_amdgcn_mfma_f32_16x16x32_bf16(b, a2[ks], acc2[nt], 0, 0, 0);
            }

        u16* op = out + (size_t)(r0 + c) * 128 + kg * 4;
#pragma unroll
        for (int nt = 0; nt < 8; ++nt) {
            uint2 pkv;
            pkv.x = pk2(fmaxf(acc2[nt][0] + b2q[nt][0], 0.f), fmaxf(acc2[nt][1] + b2q[nt][1], 0.f));
            pkv.y = pk2(fmaxf(acc2[nt][2] + b2q[nt][2], 0.f), fmaxf(acc2[nt][3] + b2q[nt][3], 0.f));
            *(uint2*)(op + nt * 16) = pkv;
        }
    }
}

// ---- fused child embed (2 layers) + RW_c pass; 512 threads, 104KB LDS ----
// ch0 = relu(relu(A@W1+b1)@W2+b2);  rw = ch0@WL + bl
__global__ __launch_bounds__(512) void embed_c_rw(
    const u16* __restrict__ A, const u16* __restrict__ W1,
    const float* __restrict__ b1, const u16* __restrict__ W2,
    const float* __restrict__ b2, const u16* __restrict__ WL,
    const float* __restrict__ bl, u16* __restrict__ ch0,
    u16* __restrict__ rw, int M)
{
    __shared__ u16 w2s[128 * 136];
    __shared__ u16 wls[128 * 136];
    __shared__ u16 tile[8][16 * 136];
    const int tid = threadIdx.x;
    for (int i = tid; i < 16384; i += 512) {
        int w = i >> 13, j = i & 8191;
        int col = j >> 6, kp = (j & 63) << 1;
        u16* d = w ? wls : w2s;
        const u16* s = w ? WL : W2;
        *(unsigned*)&d[col * 136 + kp] = *(const unsigned*)&s[(size_t)col * 128 + kp];
    }
    __syncthreads();

    const int lane = tid & 63;
    const int c = lane & 15;
    const int kg = lane >> 4;
    const int wv = tid >> 6;
    const int wid = blockIdx.x * 8 + wv;
    const int ws = gridDim.x * 8;
    const int items = M >> 4;
    u16* tl = tile[wv];

    const u16* wbase = W1 + (size_t)c * 96 + kg * 8;
    s8v bp1[3][8];
#pragma unroll
    for (int ks = 0; ks < 3; ++ks)
#pragma unroll
        for (int nt = 0; nt < 8; ++nt)
            bp1[ks][nt] = *(const s8v*)(wbase + ((size_t)nt * 16) * 96 + ks * 32);

    f4v b1q[8], b2q[8], blq[8];
#pragma unroll
    for (int nt = 0; nt < 8; ++nt) {
        b1q[nt] = *(const f4v*)(b1 + nt * 16 + kg * 4);
        b2q[nt] = *(const f4v*)(b2 + nt * 16 + kg * 4);
        blq[nt] = *(const f4v*)(bl + nt * 16 + kg * 4);
    }

    for (int item = wid; item < items; item += ws) {
        const int r0 = item << 4;
        const u16* ap = A + (size_t)(r0 + c) * 96 + kg * 8;
        s8v a[3];
#pragma unroll
        for (int ks = 0; ks < 3; ++ks) a[ks] = *(const s8v*)(ap + ks * 32);

        f4v acc[8];
#pragma unroll
        for (int nt = 0; nt < 8; ++nt) acc[nt] = (f4v){0.f, 0.f, 0.f, 0.f};
#pragma unroll
        for (int ks = 0; ks < 3; ++ks)
#pragma unroll
            for (int nt = 0; nt < 8; ++nt)
                acc[nt] = __builtin_amdgcn_mfma_f32_16x16x32_bf16(bp1[ks][nt], a[ks], acc[nt], 0, 0, 0);

#pragma unroll
        for (int nt = 0; nt < 8; ++nt) {
            uint2 pkv;
            pkv.x = pk2(fmaxf(acc[nt][0] + b1q[nt][0], 0.f), fmaxf(acc[nt][1] + b1q[nt][1], 0.f));
            pkv.y = pk2(fmaxf(acc[nt][2] + b1q[nt][2], 0.f), fmaxf(acc[nt][3] + b1q[nt][3], 0.f));
            *(uint2*)&tl[c * 136 + nt * 16 + kg * 4] = pkv;
        }

        s8v a2[4];
#pragma unroll
        for (int ks = 0; ks < 4; ++ks)
            a2[ks] = *(const s8v*)&tl[c * 136 + ks * 32 + kg * 8];

#pragma unroll
        for (int nt = 0; nt < 8; ++nt) acc[nt] = (f4v){0.f, 0.f, 0.f, 0.f};
#pragma unroll
        for (int ks = 0; ks < 4; ++ks)
#pragma unroll
            for (int nt = 0; nt < 8; ++nt) {
                s8v b = *(const s8v*)&w2s[(size_t)(nt * 16 + c) * 136 + ks * 32 + kg * 8];
                acc[nt] = __builtin_amdgcn_mfma_f32_16x16x32_bf16(b, a2[ks], acc[nt], 0, 0, 0);
            }

        u16* op = ch0 + (size_t)(r0 + c) * 128 + kg * 4;
#pragma unroll
        for (int nt = 0; nt < 8; ++nt) {
            uint2 pkv;
            pkv.x = pk2(fmaxf(acc[nt][0] + b2q[nt][0], 0.f), fmaxf(acc[nt][1] + b2q[nt][1], 0.f));
            pkv.y = pk2(fmaxf(acc[nt][2] + b2q[nt][2], 0.f), fmaxf(acc[nt][3] + b2q[nt][3], 0.f));
            *(uint2*)(op + nt * 16) = pkv;
            *(uint2*)&tl[c * 136 + nt * 16 + kg * 4] = pkv;   // bounce ch0
        }

#pragma unroll
        for (int ks = 0; ks < 4; ++ks)
            a2[ks] = *(const s8v*)&tl[c * 136 + ks * 32 + kg * 8];

#pragma unroll
        for (int nt = 0; nt < 8; ++nt) acc[nt] = (f4v){0.f, 0.f, 0.f, 0.f};
#pragma unroll
        for (int ks = 0; ks < 4; ++ks)
#pragma unroll
            for (int nt = 0; nt < 8; ++nt) {
                s8v b = *(const s8v*)&wls[(size_t)(nt * 16 + c) * 136 + ks * 32 + kg * 8];
                acc[nt] = __builtin_amdgcn_mfma_f32_16x16x32_bf16(b, a2[ks], acc[nt], 0, 0, 0);
            }

        u16* rp = rw + (size_t)(r0 + c) * 128 + kg * 4;
#pragma unroll
        for (int nt = 0; nt < 8; ++nt) {
            uint2 pkv;
            pkv.x = pk2(acc[nt][0] + blq[nt][0], acc[nt][1] + blq[nt][1]);
            pkv.y = pk2(acc[nt][2] + blq[nt][2], acc[nt][3] + blq[nt][3]);
            *(uint2*)(rp + nt * 16) = pkv;
        }
    }
}

// ---- transposed register-persistent GEMM (plain: no A2) ----
template <int KS1, bool RELU>
__global__ __launch_bounds__(256) void gemm_rb(
    const u16* __restrict__ A1, const u16* __restrict__ WT1,
    const float* __restrict__ bias0, u16* __restrict__ out, int M)
{
    constexpr int K1 = KS1 * 32;
    const int lane = threadIdx.x & 63;
    const int c = lane & 15;
    const int kg = lane >> 4;
    const int wid = blockIdx.x * 4 + (threadIdx.x >> 6);
    const int ws = gridDim.x * 4;
    const int items = M >> 4;

    const u16* wbase = WT1 + (size_t)c * K1 + kg * 8;
    s8v bp[KS1][8];
#pragma unroll
    for (int ks = 0; ks < KS1; ++ks)
#pragma unroll
        for (int nt = 0; nt < 8; ++nt)
            bp[ks][nt] = *(const s8v*)(wbase + ((size_t)nt * 16) * K1 + ks * 32);

    f4v bq[8];
#pragma unroll
    for (int nt = 0; nt < 8; ++nt)
        bq[nt] = bias0 ? *(const f4v*)(bias0 + nt * 16 + kg * 4)
                       : (f4v){0.f, 0.f, 0.f, 0.f};

    auto lda = [&](s8v* a, int item) {
        const u16* ap = A1 + (size_t)((item << 4) + c) * K1 + kg * 8;
#pragma unroll
        for (int ks = 0; ks < KS1; ++ks) a[ks] = *(const s8v*)(ap + ks * 32);
    };

    s8v a[KS1], an[KS1], a2[KS1];
    int item = wid;
    if (item < items) lda(a, item);
    if (item + ws < items) lda(an, item + ws);
    while (item < items) {
        const int i2 = item + 2 * ws;
        if (i2 < items) lda(a2, i2);

        f4v acc[8];
#pragma unroll
        for (int nt = 0; nt < 8; ++nt) acc[nt] = (f4v){0.f, 0.f, 0.f, 0.f};
#pragma unroll
        for (int ks = 0; ks < KS1; ++ks)
#pragma unroll
            for (int nt = 0; nt < 8; ++nt)
                acc[nt] = __builtin_amdgcn_mfma_f32_16x16x32_bf16(bp[ks][nt], a[ks], acc[nt], 0, 0, 0);

        const int r0 = item << 4;
        u16* op = out + (size_t)(r0 + c) * 128 + kg * 4;
#pragma unroll
        for (int nt = 0; nt < 8; ++nt) {
            float v0 = acc[nt][0] + bq[nt][0];
            float v1 = acc[nt][1] + bq[nt][1];
            float v2 = acc[nt][2] + bq[nt][2];
            float v3 = acc[nt][3] + bq[nt][3];
            if (RELU) {
                v0 = fmaxf(v0, 0.f); v1 = fmaxf(v1, 0.f);
                v2 = fmaxf(v2, 0.f); v3 = fmaxf(v3, 0.f);
            }
            uint2 pkv;
            pkv.x = pk2(v0, v1);
            pkv.y = pk2(v2, v3);
            *(uint2*)(op + nt * 16) = pkv;
        }

#pragma unroll
        for (int ks = 0; ks < KS1; ++ks) { a[ks] = an[ks]; an[ks] = a2[ks]; }
        item += ws;
    }
}

// ---- conv_fused: h=relu(Sdiv@WT1 + A2@WT2 + b0 + g*b1) -> LW = h@WX + cx ----
__global__ __launch_bounds__(256) void conv_fused(
    const u16* __restrict__ Sdiv, const u16* __restrict__ A2,
    const u16* __restrict__ WT1, const u16* __restrict__ WT2,
    const float* __restrict__ bias0, const float* __restrict__ bias1,
    const float* __restrict__ gate, const u16* __restrict__ WX,
    const float* __restrict__ cx, u16* __restrict__ out, int M)
{
    __shared__ u16 wxs[128 * 136];
    __shared__ u16 tile[4][16 * 136];
    const int tid = threadIdx.x;
    for (int i = tid; i < 8192; i += 256) {
        int col = i >> 6, kp = (i & 63) << 1;
        *(unsigned*)&wxs[col * 136 + kp] = *(const unsigned*)&WX[(size_t)col * 128 + kp];
    }
    __syncthreads();

    const int lane = tid & 63;
    const int c = lane & 15;
    const int kg = lane >> 4;
    const int wv = tid >> 6;
    const int wid = blockIdx.x * 4 + wv;
    const int ws = gridDim.x * 4;
    const int items = M >> 4;
    u16* tl = tile[wv];

    const u16* wbase = WT1 + (size_t)c * 128 + kg * 8;
    s8v bp[4][8];
#pragma unroll
    for (int ks = 0; ks < 4; ++ks)
#pragma unroll
        for (int nt = 0; nt < 8; ++nt)
            bp[ks][nt] = *(const s8v*)(wbase + ((size_t)nt * 16) * 128 + ks * 32);
    const u16* wbase2 = WT2 + (size_t)c * 128 + kg * 8;

    f4v b0q[8], b1q[8], cxq[8];
#pragma unroll
    for (int nt = 0; nt < 8; ++nt) {
        b0q[nt] = *(const f4v*)(bias0 + nt * 16 + kg * 4);
        b1q[nt] = *(const f4v*)(bias1 + nt * 16 + kg * 4);
        cxq[nt] = *(const f4v*)(cx + nt * 16 + kg * 4);
    }

    for (int item = wid; item < items; item += ws) {
        const int r0 = item << 4;
        const u16* ap = Sdiv + (size_t)(r0 + c) * 128 + kg * 8;
        const u16* ap2 = A2 + (size_t)(r0 + c) * 128 + kg * 8;
        s8v a[8];
#pragma unroll
        for (int ks = 0; ks < 4; ++ks) {
            a[ks] = *(const s8v*)(ap + ks * 32);
            a[4 + ks] = *(const s8v*)(ap2 + ks * 32);
        }

        f4v acc[8];
#pragma unroll
        for (int nt = 0; nt < 8; ++nt) acc[nt] = (f4v){0.f, 0.f, 0.f, 0.f};
#pragma unroll
        for (int ks = 0; ks < 4; ++ks)
#pragma unroll
            for (int nt = 0; nt < 8; ++nt)
                acc[nt] = __builtin_amdgcn_mfma_f32_16x16x32_bf16(bp[ks][nt], a[ks], acc[nt], 0, 0, 0);
#pragma unroll
        for (int ks = 0; ks < 4; ++ks)
#pragma unroll
            for (int nt = 0; nt < 8; ++nt) {
                s8v b = *(const s8v*)(wbase2 + ((size_t)nt * 16) * 128 + ks * 32);
                acc[nt] = __builtin_amdgcn_mfma_f32_16x16x32_bf16(b, a[4 + ks], acc[nt], 0, 0, 0);
            }

        const float g = (gate[r0 + c] > 0.f) ? 1.f : 0.f;
#pragma unroll
        for (int nt = 0; nt < 8; ++nt) {
            uint2 pkv;
            pkv.x = pk2(fmaxf(acc[nt][0] + b0q[nt][0] + g * b1q[nt][0], 0.f),
                        fmaxf(acc[nt][1] + b0q[nt][1] + g * b1q[nt][1], 0.f));
            pkv.y = pk2(fmaxf(acc[nt][2] + b0q[nt][2] + g * b1q[nt][2], 0.f),
                        fmaxf(acc[nt][3] + b0q[nt][3] + g * b1q[nt][3], 0.f));
            *(uint2*)&tl[c * 136 + nt * 16 + kg * 4] = pkv;
        }

        s8v a2[4];
#pragma unroll
        for (int ks = 0; ks < 4; ++ks)
            a2[ks] = *(const s8v*)&tl[c * 136 + ks * 32 + kg * 8];

#pragma unroll
        for (int nt = 0; nt < 8; ++nt) acc[nt] = (f4v){0.f, 0.f, 0.f, 0.f};
#pragma unroll
        for (int ks = 0; ks < 4; ++ks)
#pragma unroll
            for (int nt = 0; nt < 8; ++nt) {
                s8v b = *(const s8v*)&wxs[(size_t)(nt * 16 + c) * 136 + ks * 32 + kg * 8];
                acc[nt] = __builtin_amdgcn_mfma_f32_16x16x32_bf16(b, a2[ks], acc[nt], 0, 0, 0);
            }

        u16* op = out + (size_t)(r0 + c) * 128 + kg * 4;
#pragma unroll
        for (int nt = 0; nt < 8; ++nt) {
            uint2 pkv;
            pkv.x = pk2(acc[nt][0] + cxq[nt][0], acc[nt][1] + cxq[nt][1]);
            pkv.y = pk2(acc[nt][2] + cxq[nt][2], acc[nt][3] + cxq[nt][3]);
            *(uint2*)(op + nt * 16) = pkv;
        }
    }
}

// ---- conv_head: h=relu(stage1) -> t=relu(h@WH+bh) -> sigmoid(t.w2+b2) ----
__global__ __launch_bounds__(256) void conv_head(
    const u16* __restrict__ Sdiv, const u16* __restrict__ A2,
    const u16* __restrict__ WT1, const u16* __restrict__ WT2,
    const float* __restrict__ bias0, const float* __restrict__ bias1,
    const float* __restrict__ gate, const u16* __restrict__ WH,
    const float* __restrict__ bh, const float* __restrict__ w2,
    const float* __restrict__ b2, float* __restrict__ outp, int M)
{
    __shared__ u16 whs[128 * 136];
    __shared__ u16 tile[4][16 * 136];
    const int tid = threadIdx.x;
    for (int i = tid; i < 8192; i += 256) {
        int col = i >> 6, kp = (i & 63) << 1;
        *(unsigned*)&whs[col * 136 + kp] = *(const unsigned*)&WH[(size_t)col * 128 + kp];
    }
    __syncthreads();

    const int lane = tid & 63;
    const int c = lane & 15;
    const int kg = lane >> 4;
    const int wv = tid >> 6;
    const int wid = blockIdx.x * 4 + wv;
    const int ws = gridDim.x * 4;
    const int items = M >> 4;
    u16* tl = tile[wv];

    const u16* wbase = WT1 + (size_t)c * 128 + kg * 8;
    s8v bp[4][8];
#pragma unroll
    for (int ks = 0; ks < 4; ++ks)
#pragma unroll
        for (int nt = 0; nt < 8; ++nt)
            bp[ks][nt] = *(const s8v*)(wbase + ((size_t)nt * 16) * 128 + ks * 32);
    const u16* wbase2 = WT2 + (size_t)c * 128 + kg * 8;

    f4v b0q[8], b1q[8], bhq[8];
#pragma unroll
    for (int nt = 0; nt < 8; ++nt) {
        b0q[nt] = *(const f4v*)(bias0 + nt * 16 + kg * 4);
        b1q[nt] = *(const f4v*)(bias1 + nt * 16 + kg * 4);
        bhq[nt] = *(const f4v*)(bh + nt * 16 + kg * 4);
    }
    const float s0 = b2[0], s1 = b2[1];

    for (int item = wid; item < items; item += ws) {
        const int r0 = item << 4;
        const u16* ap = Sdiv + (size_t)(r0 + c) * 128 + kg * 8;
        const u16* ap2 = A2 + (size_t)(r0 + c) * 128 + kg * 8;
        s8v a[8];
#pragma unroll
        for (int ks = 0; ks < 4; ++ks) {
            a[ks] = *(const s8v*)(ap + ks * 32);
            a[4 + ks] = *(const s8v*)(ap2 + ks * 32);
        }

        f4v acc[8];
#pragma unroll
        for (int nt = 0; nt < 8; ++nt) acc[nt] = (f4v){0.f, 0.f, 0.f, 0.f};
#pragma unroll
        for (int ks = 0; ks < 4; ++ks)
#pragma unroll
            for (int nt = 0; nt < 8; ++nt)
                acc[nt] = __builtin_amdgcn_mfma_f32_16x16x32_bf16(bp[ks][nt], a[ks], acc[nt], 0, 0, 0);
#pragma unroll
        for (int ks = 0; ks < 4; ++ks)
#pragma unroll
            for (int nt = 0; nt < 8; ++nt) {
                s8v b = *(const s8v*)(wbase2 + ((size_t)nt * 16) * 128 + ks * 32);
                acc[nt] = __builtin_amdgcn_mfma_f32_16x16x32_bf16(b, a[4 + ks], acc[nt], 0, 0, 0);
            }

        const float g = (gate[r0 + c] > 0.f) ? 1.f : 0.f;
#pragma unroll
        for (int nt = 0; nt < 8; ++nt) {
            uint2 pkv;
            pkv.x = pk2(fmaxf(acc[nt][0] + b0q[nt][0] + g * b1q[nt][0], 0.f),
                        fmaxf(acc[nt][1] + b0q[nt][1] + g * b1q[nt][1], 0.f));
            pkv.y = pk2(fmaxf(acc[nt][2] + b0q[nt][2] + g * b1q[nt][2], 0.f),
                        fmaxf(acc[nt][3] + b0q[nt][3] + g * b1q[nt][3], 0.f));
            *(uint2*)&tl[c * 136 + nt * 16 + kg * 4] = pkv;
        }

        s8v a2[4];
#pragma unroll
        for (int ks = 0; ks < 4; ++ks)
            a2[ks] = *(const s8v*)&tl[c * 136 + ks * 32 + kg * 8];

#pragma unroll
        for (int nt = 0; nt < 8; ++nt) acc[nt] = (f4v){0.f, 0.f, 0.f, 0.f};
#pragma unroll
        for (int ks = 0; ks < 4; ++ks)
#pragma unroll
            for (int nt = 0; nt < 8; ++nt) {
                s8v b = *(const s8v*)&whs[(size_t)(nt * 16 + c) * 136 + ks * 32 + kg * 8];
                acc[nt] = __builtin_amdgcn_mfma_f32_16x16x32_bf16(b, a2[ks], acc[nt], 0, 0, 0);
            }

        float p0 = 0.f, p1 = 0.f;
#pragma unroll
        for (int nt = 0; nt < 8; ++nt) {
            float v0 = fmaxf(acc[nt][0] + bhq[nt][0], 0.f);
            float v1 = fmaxf(acc[nt][1] + bhq[nt][1], 0.f);
            float v2 = fmaxf(acc[nt][2] + bhq[nt][2], 0.f);
            float v3 = fmaxf(acc[nt][3] + bhq[nt][3], 0.f);
            const float4 wa = *(const float4*)(w2 + (nt * 16 + kg * 4) * 2);
            const float4 wb = *(const float4*)(w2 + (nt * 16 + kg * 4) * 2 + 4);
            p0 += v0 * wa.x + v1 * wa.z + v2 * wb.x + v3 * wb.z;
            p1 += v0 * wa.y + v1 * wa.w + v2 * wb.y + v3 * wb.w;
        }
        p0 += __shfl_xor(p0, 16); p0 += __shfl_xor(p0, 32);
        p1 += __shfl_xor(p1, 16); p1 += __shfl_xor(p1, 32);
        if (kg == 0) {
            float2 o;
            o.x = 1.f / (1.f + expf(-(p0 + s0)));
            o.y = 1.f / (1.f + expf(-(p1 + s1)));
            *(float2*)(outp + (size_t)(r0 + c) * 2) = o;
        }
    }
}

// ============================ CSR counting sort ============================
__global__ __launch_bounds__(256) void binA(
    const int* __restrict__ src, const int* __restrict__ dst,
    int E, int CH, int NB, int nbk_c, int NBK,
    int* __restrict__ G, int* __restrict__ Tb)
{
    __shared__ int h[1024];
    const int blk = blockIdx.x, tid = threadIdx.x;
    for (int i = tid; i < NBK; i += 256) h[i] = 0;
    __syncthreads();
    const int e0 = blk * CH, e1 = min(E, e0 + CH);
    for (int e = e0 + tid; e < e1; e += 256) {
        atomicAdd(&h[dst[e] >> 9], 1);
        atomicAdd(&h[nbk_c + (src[e] >> 9)], 1);
    }
    __syncthreads();
    for (int b = tid; b < NBK; b += 256) {
        const int v = h[b];
        G[b * NB + blk] = v;
        if (v) atomicAdd(&Tb[b], v);
    }
}

__global__ __launch_bounds__(512) void binS(
    const int* __restrict__ Tb, int NBK, int* __restrict__ BB)
{
    __shared__ int wsum[8];
    const int tid = threadIdx.x;
    const int T = (tid < NBK) ? Tb[tid] : 0;
    const int lane = tid & 63, wv = tid >> 6;
    int incl = T;
#pragma unroll
    for (int d = 1; d < 64; d <<= 1) {
        int up = __shfl_up(incl, d);
        if (lane >= d) incl += up;
    }
    if (lane == 63) wsum[wv] = incl;
    __syncthreads();
    if (tid == 0) {
        int run = 0;
        for (int w = 0; w < 8; ++w) { int t = wsum[w]; wsum[w] = run; run += t; }
    }
    __syncthreads();
    const int base = wsum[wv] + incl - T;
    if (tid < NBK) {
        BB[tid] = base;
        if (tid == NBK - 1) BB[NBK] = base + T;
    }
}

__global__ __launch_bounds__(64) void binP(
    const int* __restrict__ G, const int* __restrict__ BB,
    int NB, int* __restrict__ PBB)
{
    const int b = blockIdx.x, l = threadIdx.x;
    const int* g = G + (size_t)b * NB;
    const int v0 = (l < NB) ? g[l] : 0;
    const int v1 = (l + 64 < NB) ? g[l + 64] : 0;
    int i0 = v0, i1 = v1;
#pragma unroll
    for (int d = 1; d < 64; d <<= 1) {
        int u0 = __shfl_up(i0, d);
        int u1 = __shfl_up(i1, d);
        if (l >= d) { i0 += u0; i1 += u1; }
    }
    const int t0 = __shfl(i0, 63);
    const int base = BB[b];
    int* p = PBB + (size_t)b * NB;
    if (l < NB) p[l] = base + i0 - v0;
    if (l + 64 < NB) p[l + 64] = base + t0 + i1 - v1;
}

__global__ __launch_bounds__(256) void binB(
    const int* __restrict__ src, const int* __restrict__ dst,
    int E, int CH, int NB, int nbk_c, int NBK,
    const int* __restrict__ PBB, unsigned* __restrict__ REC)
{
    __shared__ int fill[1024];
    const int blk = blockIdx.x, tid = threadIdx.x;
    for (int i = tid; i < NBK; i += 256) fill[i] = 0;
    __syncthreads();
    const int e0 = blk * CH, e1 = min(E, e0 + CH);
    for (int e = e0 + tid; e < e1; e += 256) {
        const int s = src[e], d = dst[e];
        const int bc = d >> 9;
        const int pc = PBB[bc * NB + blk] + atomicAdd(&fill[bc], 1);
        REC[pc] = (unsigned)s | ((unsigned)(d & 511) << 17);
        const int bp = nbk_c + (s >> 9);
        const int pp = PBB[bp * NB + blk] + atomicAdd(&fill[bp], 1);
        REC[pp] = (unsigned)d | ((unsigned)(s & 511) << 17);
    }
}

__global__ __launch_bounds__(256) void binC2(
    const unsigned* __restrict__ REC, const int* __restrict__ BB,
    int nbk_c, int NCn, int NPn,
    int* __restrict__ off_c, int* __restrict__ cnt_c,
    int* __restrict__ off_p, int* __restrict__ cnt_p, int* __restrict__ AJ)
{
    __shared__ int nh[512], lo[512], fl[512], ws2[4];
    const int b = blockIdx.x, tid = threadIdx.x;
    int Nn, node0;
    int *off_out, *cnt_out;
    if (b < nbk_c) { Nn = NCn; node0 = b << 9; off_out = off_c; cnt_out = cnt_c; }
    else { Nn = NPn; node0 = (b - nbk_c) << 9; off_out = off_p; cnt_out = cnt_p; }
    const int r0 = BB[b], r1 = BB[b + 1];
    const int kmax = min(512, Nn - node0);
    nh[tid] = 0; nh[tid + 256] = 0;
    fl[tid] = 0; fl[tid + 256] = 0;
    __syncthreads();
    for (int i = r0 + tid; i < r1; i += 256)
        atomicAdd(&nh[REC[i] >> 17], 1);
    __syncthreads();
    const int v0 = nh[2 * tid], v1 = nh[2 * tid + 1];
    const int s = v0 + v1;
    const int lane = tid & 63, wv = tid >> 6;
    int incl = s;
#pragma unroll
    for (int d = 1; d < 64; d <<= 1) {
        int up = __shfl_up(incl, d);
        if (lane >= d) incl += up;
    }
    if (lane == 63) ws2[wv] = incl;
    __syncthreads();
    if (tid == 0) {
        int run = 0;
        for (int w = 0; w < 4; ++w) { int t = ws2[w]; ws2[w] = run; run += t; }
    }
    __syncthreads();
    const int base = ws2[wv] + incl - s;
    lo[2 * tid] = base;
    lo[2 * tid + 1] = base + v0;
    __syncthreads();
    for (int k = tid; k < kmax; k += 256) {
        off_out[node0 + k] = r0 + lo[k];
        cnt_out[node0 + k] = nh[k];
    }
    for (int i = r0 + tid; i < r1; i += 256) {
        const unsigned rec = REC[i];
        const int k = rec >> 17;
        const int pos = r0 + lo[k] + atomicAdd(&fl[k], 1);
        AJ[pos] = (int)(rec & 0x1FFFFu);
    }
}

// ---- gather: Sdiv[n] = mean_e relu((RW[n]+LW[adj])*sf) ----
__global__ __launch_bounds__(256) void node_gather2(
    const int* __restrict__ off, const int* __restrict__ cnt,
    const int* __restrict__ adj,
    const u16* __restrict__ RW, const u16* __restrict__ LW,
    u16* __restrict__ Sdiv, float* __restrict__ cntf,
    const float* __restrict__ sf_p, int N)
{
    int t = blockIdx.x * 256 + threadIdx.x;
    int n = t >> 5;
    if (n >= N) return;
    int l32 = t & 31;
    int c = l32 & 15;
    int half = l32 >> 4;
    const float sf = *sf_p;
    const int start = off[n], len = cnt[n];

    float rw[8];
    unpack8(*(const uint4*)(RW + (size_t)n * 128 + c * 8), rw);
    float acc[8] = {0.f, 0.f, 0.f, 0.f, 0.f, 0.f, 0.f, 0.f};

    for (int i = half; i < len; i += 2) {
        int l = adj[start + i];
        float lw[8];
        unpack8(*(const uint4*)(LW + (size_t)l * 128 + c * 8), lw);
#pragma unroll
        for (int j = 0; j < 8; ++j)
            acc[j] += fmaxf((rw[j] + lw[j]) * sf, 0.f);
    }
#pragma unroll
    for (int j = 0; j < 8; ++j) acc[j] += __shfl_xor(acc[j], 16);

    if (half == 0) {
        float inv = 1.f / fmaxf((float)len, 1.f);
        uint4 o;
        o.x = pk2(acc[0] * inv, acc[1] * inv);
        o.y = pk2(acc[2] * inv, acc[3] * inv);
        o.z = pk2(acc[4] * inv, acc[5] * inv);
        o.w = pk2(acc[6] * inv, acc[7] * inv);
        *(uint4*)(Sdiv + (size_t)n * 128 + c * 8) = o;
        if (l32 == 0) cntf[n] = (float)len;
    }
}

extern "C" void kernel_launch(void* const* d_in, const int* in_sizes, int n_in,
                              void* d_out, int out_size, void* d_ws, size_t ws_size,
                              hipStream_t stream)
{
    const float* pivot = (const float*)d_in[0];
    const float* child = (const float*)d_in[1];
    const int* edges = (const int*)d_in[2];
    const int F = in_sizes[3];           // 69
    const int NP = in_sizes[0] / F;
    const int NC = in_sizes[1] / F;
    const int E = in_sizes[2] / 2;
    const int* src = edges;
    const int* dst = edges + E;

    const float *pe_shift = (const float*)d_in[3], *pe_scale = (const float*)d_in[4],
                *pe_w1 = (const float*)d_in[5], *pe_b1 = (const float*)d_in[6],
                *pe_w2 = (const float*)d_in[7], *pe_b2 = (const float*)d_in[8];
    const float *ce_shift = (const float*)d_in[9], *ce_scale = (const float*)d_in[10],
                *ce_w1 = (const float*)d_in[11], *ce_b1 = (const float*)d_in[12],
                *ce_w2 = (const float*)d_in[13], *ce_b2 = (const float*)d_in[14];
    const float *vc_wl = (const float*)d_in[15], *vc_bl = (const float*)d_in[16],
                *vc_wr = (const float*)d_in[17], *vc_sf = (const float*)d_in[18],
                *vc_wf = (const float*)d_in[19], *vc_bf = (const float*)d_in[20],
                *vc_sp = (const float*)d_in[21], *vc_wo1 = (const float*)d_in[22],
                *vc_bo1 = (const float*)d_in[23], *vc_wo2 = (const float*)d_in[24],
                *vc_bo2 = (const float*)d_in[25];
    const float *cv_wl = (const float*)d_in[26], *cv_bl = (const float*)d_in[27],
                *cv_wr = (const float*)d_in[28], *cv_sf = (const float*)d_in[29],
                *cv_wf = (const float*)d_in[30], *cv_bf = (const float*)d_in[31],
                *cv_sp = (const float*)d_in[32], *cv_wo1 = (const float*)d_in[33],
                *cv_bo1 = (const float*)d_in[34], *cv_wo2 = (const float*)d_in[35],
                *cv_bo2 = (const float*)d_in[36];
    const float *out_w1 = (const float*)d_in[37], *out_b1 = (const float*)d_in[38],
                *out_w2 = (const float*)d_in[39], *out_b2 = (const float*)d_in[40];

    // ---- workspace carve (256B aligned) ----
    char* base = (char*)d_ws;
    size_t off = 0;
    auto carve = [&](size_t bytes) {
        void* p = base + off;
        off += (bytes + 255) & ~(size_t)255;
        return p;
    };
    float* Wsc = (float*)carve((size_t)4 * 16384 * 4);
    float* Vsc = (float*)carve((size_t)4 * 128 * 4);
    u16* WT = (u16*)carve((size_t)14 * 32768 * 2);
    u16* FPC = (u16*)carve((size_t)(NP + NC) * 96 * 2);
    u16* FP = FPC;
    u16* FC = FPC + (size_t)NP * 96;
    u16* B0 = (u16*)carve((size_t)NP * 128 * 2);   // pv0
    u16* B1 = (u16*)carve((size_t)NC * 128 * 2);   // RW_c
    u16* B2 = (u16*)carve((size_t)NC * 128 * 2);   // ch0
    u16* B3 = (u16*)carve((size_t)NC * 128 * 2);   // LW_v -> LW_c
    u16* B4 = (u16*)carve((size_t)NC * 128 * 2);   // Sdiv
    u16* B6 = (u16*)carve((size_t)NP * 128 * 2);   // RW_p
    const int NMAX = (NC > NP) ? NC : NP;
    float* cntf = (float*)carve((size_t)NMAX * 4);

    const int NB = 120;
    const int CH = (E + NB - 1) / NB;
    const int nbk_c = (NC + 511) >> 9;
    const int nbk_p = (NP + 511) >> 9;
    const int NBK = nbk_c + nbk_p;
    int* cnt_c = (int*)carve((size_t)NC * 4);
    int* cnt_p = (int*)carve((size_t)NP * 4);
    int* off_c = (int*)carve((size_t)NC * 4);
    int* off_p = (int*)carve((size_t)NP * 4);
    int* G = (int*)carve((size_t)NBK * NB * 4);
    int* PBB = (int*)carve((size_t)NBK * NB * 4);
    int* BB = (int*)carve((size_t)(NBK + 1) * 4);
    int* Tb = (int*)carve((size_t)NBK * 4);
    unsigned* REC = (unsigned*)carve((size_t)2 * E * 4);
    int* AJ = (int*)carve((size_t)2 * E * 4);

    // ---- folded weight precompute (fp32) ----
    SmPack sp;
    sp.e[0] = {vc_wf, vc_wo1, vc_sp};
    sp.e[1] = {cv_wf, cv_wo1, cv_sp};
    sp.e[2] = {vc_wo2, cv_wr, nullptr};
    sp.e[3] = {cv_wo2, out_w1, nullptr};
    hipLaunchKernelGGL(smallmm, dim3(256), dim3(256), 0, stream, sp, Wsc);
    hipLaunchKernelGGL(vecpre, dim3(1), dim3(128), 0, stream,
                       vc_bf, vc_wo1, vc_sp, cv_bf, cv_wo1, cv_sp,
                       vc_bo2, cv_wr, cv_bo2, out_w1, out_b1, Vsc);
    const float* cvec_vc = Vsc;
    const float* cvec_cv = Vsc + 128;
    const float* cx = Vsc + 256;
    const float* bh = Vsc + 384;

    // ---- weight conversion ----
    WPack wp;
    auto setw = [&](int i, const float* s, int ks, int kd) {
        wp.e[i].src = s; wp.e[i].Ksrc = ks; wp.e[i].Kdst = kd;
    };
    setw(0, pe_w1, F, 96);            setw(1, pe_w2, 128, 128);
    setw(2, ce_w1, F, 96);            setw(3, ce_w2, 128, 128);
    setw(4, vc_wl, 128, 128);         setw(5, vc_wr, 128, 128);
    setw(6, Wsc + 0 * 16384, 128, 128);
    setw(7, vc_wo1 + 128 * 128, 128, 128);
    setw(8, Wsc + 2 * 16384, 128, 128);
    setw(9, cv_wl, 128, 128);         setw(10, cv_wr, 128, 128);
    setw(11, Wsc + 1 * 16384, 128, 128);
    setw(12, cv_wo1 + 128 * 128, 128, 128);
    setw(13, Wsc + 3 * 16384, 128, 128);
    hipLaunchKernelGGL(wconvert, dim3(14 * 128), dim3(256), 0, stream, wp, WT);
    auto wt = [&](int i) { return WT + (size_t)i * 32768; };

    // ---- feature conversion ----
    hipLaunchKernelGGL(featconv2, dim3(2048), dim3(256), 0, stream,
                       pivot, child, pe_shift, pe_scale, ce_shift, ce_scale,
                       FPC, (long)NP, (long)(NP + NC) * 96, F);

    // ---- CSR via counting sort ----
    hipMemsetAsync(Tb, 0, (size_t)NBK * 4, stream);
    hipLaunchKernelGGL(binA, dim3(NB), dim3(256), 0, stream,
                       src, dst, E, CH, NB, nbk_c, NBK, G, Tb);
    hipLaunchKernelGGL(binS, dim3(1), dim3(512), 0, stream, Tb, NBK, BB);
    hipLaunchKernelGGL(binP, dim3(NBK), dim3(64), 0, stream, G, BB, NB, PBB);
    hipLaunchKernelGGL(binB, dim3(NB), dim3(256), 0, stream,
                       src, dst, E, CH, NB, nbk_c, NBK, PBB, REC);
    hipLaunchKernelGGL(binC2, dim3(NBK), dim3(256), 0, stream,
                       REC, BB, nbk_c, NC, NP, off_c, cnt_c, off_p, cnt_p, AJ);

    // ---- fused pipeline ----
    const dim3 blk(256);
    auto grd = [](int M) {
        int items = M >> 4;
        int b = (items + 3) / 4;
        return dim3((unsigned)(b < 512 ? b : 512));
    };
    auto grd8 = [](int M) {
        int items = M >> 4;
        int b = (items + 7) / 8;
        return dim3((unsigned)(b < 256 ? b : 256));
    };

    // pivot embed -> pv0
    hipLaunchKernelGGL(embed_fused, grd(NP), blk, 0, stream,
                       FP, wt(0), pe_b1, wt(1), pe_b2, B0, NP);
    // child embed + RW_c
    hipLaunchKernelGGL(embed_c_rw, grd8(NC), dim3(512), 0, stream,
                       FC, wt(2), ce_b1, wt(3), ce_b2, wt(4), vc_bl, B2, B1, NC);
    // LW_v, RW_p
    gemm_rb<4, false><<<grd(NP), blk, 0, stream>>>(B0, wt(5), nullptr, B3, NP);
    gemm_rb<4, false><<<grd(NP), blk, 0, stream>>>(B0, wt(9), cv_bl, B6, NP);

    // conv v->c
    hipLaunchKernelGGL(node_gather2, dim3(((size_t)NC * 32 + 255) / 256), blk, 0,
                       stream, off_c, cnt_c, AJ, B1, B3, B4, cntf, vc_sf, NC);
    hipLaunchKernelGGL(conv_fused, grd(NC), blk, 0, stream,
                       B4, B2, wt(6), wt(7), vc_bo1, cvec_vc, cntf,
                       wt(8), cx, B3, NC);                         // LW_c

    // conv c->v + head
    hipLaunchKernelGGL(node_gather2, dim3(((size_t)NP * 32 + 255) / 256), blk, 0,
                       stream, off_p, cnt_p, AJ, B6, B3, B4, cntf, cv_sf, NP);
    hipLaunchKernelGGL(conv_head, grd(NP), blk, 0, stream,
                       B4, B0, wt(11), wt(12), cv_bo1, cvec_cv, cntf,
                       wt(13), bh, out_w2, out_b2, (float*)d_out, NP);
}

// Round 12
// 347.601 us; speedup vs baseline: 1.4608x; 1.4608x over previous
//
#include <hip/hip_runtime.h>
#include <math.h>

// ---------------------------------------------------------------------------
// Round 12: revert to r8 (best, 362us) + only proven-safe deltas:
//   - featconv2 / binC2 dispatch merges (from r9, orthogonal)
//   - gemm_multi batching (r9 idea) but with r8's NON-transposed epilogue
//     (r9/r10 isolated the transposed epilogue as the regressor).
// All GEMM math/storage identical to r8.
// ---------------------------------------------------------------------------

typedef unsigned short u16;
typedef __attribute__((ext_vector_type(8))) short s8v;   // 8 bf16 = 4 VGPR
typedef __attribute__((ext_vector_type(4))) float f4v;   // MFMA C/D frag

__device__ __forceinline__ float bf2f(u16 u) {
    unsigned x = ((unsigned)u) << 16;
    return __builtin_bit_cast(float, x);
}
__device__ __forceinline__ u16 f2bf(float f) {
    unsigned x = __builtin_bit_cast(unsigned, f);
    unsigned r = x + 0x7fffu + ((x >> 16) & 1u);
    return (u16)(r >> 16);
}
__device__ __forceinline__ unsigned pk2(float a, float b) {
    return (unsigned)f2bf(a) | ((unsigned)f2bf(b) << 16);
}
__device__ __forceinline__ void unpack8(uint4 u, float* f) {
    f[0] = bf2f((u16)(u.x & 0xffff)); f[1] = bf2f((u16)(u.x >> 16));
    f[2] = bf2f((u16)(u.y & 0xffff)); f[3] = bf2f((u16)(u.y >> 16));
    f[4] = bf2f((u16)(u.z & 0xffff)); f[5] = bf2f((u16)(u.z >> 16));
    f[6] = bf2f((u16)(u.w & 0xffff)); f[7] = bf2f((u16)(u.w >> 16));
}

// ---- small fp32 128x128 matmuls for folded weights ----
struct SmEnt { const float* A; const float* B; const float* s; };
struct SmPack { SmEnt e[4]; };

__global__ __launch_bounds__(256) void smallmm(SmPack p, float* __restrict__ out)
{
    int t = blockIdx.x * 256 + threadIdx.x;
    int m = t >> 14;
    int o = t & 16383;
    int i = o >> 7, j = o & 127;
    SmEnt en = p.e[m];
    float acc = 0.f;
#pragma unroll 4
    for (int k = 0; k < 128; ++k) acc += en.A[i * 128 + k] * en.B[k * 128 + j];
    if (en.s) acc *= *en.s;
    out[(size_t)m * 16384 + o] = acc;
}

__global__ void vecpre(
    const float* vc_bf, const float* vc_wo1, const float* vc_sp,
    const float* cv_bf, const float* cv_wo1, const float* cv_sp,
    const float* vc_bo2, const float* cv_wr,
    const float* cv_bo2, const float* out_w1, const float* out_b1,
    float* __restrict__ vout)
{
    int j = threadIdx.x;
    if (j >= 128) return;
    float a0 = 0.f, a1 = 0.f, a2 = 0.f, a3 = 0.f;
    for (int k = 0; k < 128; ++k) {
        a0 += vc_bf[k] * vc_wo1[k * 128 + j];
        a1 += cv_bf[k] * cv_wo1[k * 128 + j];
        a2 += vc_bo2[k] * cv_wr[k * 128 + j];
        a3 += cv_bo2[k] * out_w1[k * 128 + j];
    }
    vout[j] = a0 * (*vc_sp);
    vout[128 + j] = a1 * (*cv_sp);
    vout[256 + j] = a2;
    vout[384 + j] = a3 + out_b1[j];
}

// ---- weight conversion: fp32 [Ksrc][128] -> bf16 WT[col*Kdst + k], pad k ----
struct WEnt { const float* src; int Ksrc; int Kdst; };
struct WPack { WEnt e[14]; };

__global__ __launch_bounds__(256) void wconvert(WPack p, u16* __restrict__ wt)
{
    int t = blockIdx.x * 256 + threadIdx.x;
    int m = t >> 15;
    int i = t & 32767;
    WEnt en = p.e[m];
    if (i >= (en.Kdst << 7)) return;
    int k = i >> 7, col = i & 127;
    float v = (k < en.Ksrc) ? en.src[k * 128 + col] : 0.f;
    wt[(size_t)m * 32768 + (size_t)col * en.Kdst + k] = f2bf(v);
}

// ---- feature conversion (both tables): fp32 [M,F]+prenorm -> bf16 [M,96] ----
__global__ __launch_bounds__(256) void featconv2(
    const float* __restrict__ pv, const float* __restrict__ ch,
    const float* __restrict__ psh, const float* __restrict__ psc,
    const float* __restrict__ csh, const float* __restrict__ csc,
    u16* __restrict__ y, long NPr, long total, int F)
{
    for (long i = (long)blockIdx.x * 256 + threadIdx.x; i < total;
         i += (long)gridDim.x * 256) {
        int cc = (int)(i % 96);
        long r = i / 96;
        const float *x, *sh, *sc;
        long row;
        if (r < NPr) { x = pv; sh = psh; sc = psc; row = r; }
        else { x = ch; sh = csh; sc = csc; row = r - NPr; }
        float v = 0.f;
        if (cc < F) {
            v = x[row * F + cc];
            v = (v + sh[cc]) * sc[cc];
        }
        y[i] = f2bf(v);
    }
}

// ---- register-persistent-B GEMM (r8 epilogue) ----
template <int KS1, bool HASA2, bool RELU, bool GATE>
__global__ __launch_bounds__(256) void gemm_rb(
    const u16* __restrict__ A1, const u16* __restrict__ A2,
    const u16* __restrict__ WT1,     // bf16 [128][KS1*32]
    const u16* __restrict__ WT2,     // bf16 [128][128] (when HASA2)
    const float* __restrict__ bias0, // fp32 [128] or null
    const float* __restrict__ bias1, // fp32 [128] or null (gated)
    const float* __restrict__ gate,  // fp32 [M] (cnt) when GATE
    u16* __restrict__ out, int M)    // M % 16 == 0
{
    constexpr int K1 = KS1 * 32;
    constexpr bool PF = !HASA2;
    constexpr int AS = KS1 + (HASA2 ? 4 : 0);
    const int lane = threadIdx.x & 63;
    const int c = lane & 15;
    const int kg = lane >> 4;
    const int wid = blockIdx.x * 4 + (threadIdx.x >> 6);
    const int ws = gridDim.x * 4;
    const int items = M >> 4;

    const u16* wbase = WT1 + (size_t)c * K1 + kg * 8;
    s8v bp[KS1][8];
#pragma unroll
    for (int ks = 0; ks < KS1; ++ks)
#pragma unroll
        for (int nt = 0; nt < 8; ++nt)
            bp[ks][nt] = *(const s8v*)(wbase + ((size_t)nt * 16) * K1 + ks * 32);

    const u16* wbase2 = HASA2 ? (WT2 + (size_t)c * 128 + kg * 8) : nullptr;

    float bc0[8], bc1[8];
#pragma unroll
    for (int nt = 0; nt < 8; ++nt) {
        bc0[nt] = bias0 ? bias0[nt * 16 + c] : 0.f;
        bc1[nt] = (GATE && bias1) ? bias1[nt * 16 + c] : 0.f;
    }

    auto lda = [&](s8v* a, int item) {
        const u16* ap = A1 + (size_t)((item << 4) + c) * K1 + kg * 8;
#pragma unroll
        for (int ks = 0; ks < KS1; ++ks) a[ks] = *(const s8v*)(ap + ks * 32);
        if (HASA2) {
            const u16* ap2 = A2 + (size_t)((item << 4) + c) * 128 + kg * 8;
#pragma unroll
            for (int ks = 0; ks < 4; ++ks) a[KS1 + ks] = *(const s8v*)(ap2 + ks * 32);
        }
    };

    s8v a[AS], an[AS], a2[AS];
    int item = wid;
    if (item < items) lda(a, item);
    if (PF && item + ws < items) lda(an, item + ws);
    while (item < items) {
        const int i2 = item + 2 * ws;
        if (PF && i2 < items) lda(a2, i2);

        f4v acc[8];
#pragma unroll
        for (int nt = 0; nt < 8; ++nt) acc[nt] = (f4v){0.f, 0.f, 0.f, 0.f};
#pragma unroll
        for (int ks = 0; ks < KS1; ++ks)
#pragma unroll
            for (int nt = 0; nt < 8; ++nt)
                acc[nt] = __builtin_amdgcn_mfma_f32_16x16x32_bf16(a[ks], bp[ks][nt], acc[nt], 0, 0, 0);
        if (HASA2) {
#pragma unroll
            for (int ks = 0; ks < 4; ++ks)
#pragma unroll
                for (int nt = 0; nt < 8; ++nt) {
                    s8v b = *(const s8v*)(wbase2 + ((size_t)nt * 16) * 128 + ks * 32);
                    acc[nt] = __builtin_amdgcn_mfma_f32_16x16x32_bf16(a[KS1 + ks], b, acc[nt], 0, 0, 0);
                }
        }

        const int r0 = item << 4;
        float g4[4];
#pragma unroll
        for (int j = 0; j < 4; ++j)
            g4[j] = GATE ? (gate[r0 + kg * 4 + j] > 0.f ? 1.f : 0.f) : 0.f;
#pragma unroll
        for (int nt = 0; nt < 8; ++nt)
#pragma unroll
            for (int j = 0; j < 4; ++j) {
                float v = acc[nt][j] + bc0[nt] + g4[j] * bc1[nt];
                if (RELU) v = fmaxf(v, 0.f);
                out[(size_t)(r0 + kg * 4 + j) * 128 + nt * 16 + c] = f2bf(v);
            }

        if (PF) {
#pragma unroll
            for (int ks = 0; ks < AS; ++ks) { a[ks] = an[ks]; an[ks] = a2[ks]; }
        } else if (item + ws < items) {
            lda(a, item + ws);
        }
        item += ws;
    }
}

// ---- multi-job GEMM (r8 epilogue, independent same-K jobs via grid.y) ----
struct GJob { const u16* A1; const u16* WT1; const float* bias0; u16* out; int M; };
struct GJobs3 { GJob j[3]; };

template <int KS1, bool RELU>
__global__ __launch_bounds__(256) void gemm_multi(GJobs3 jobs)
{
    constexpr int K1 = KS1 * 32;
    const GJob jb = jobs.j[blockIdx.y];
    const u16* __restrict__ A1 = jb.A1;
    const float* __restrict__ bias0 = jb.bias0;
    u16* __restrict__ out = jb.out;
    const int lane = threadIdx.x & 63;
    const int c = lane & 15;
    const int kg = lane >> 4;
    const int wid = blockIdx.x * 4 + (threadIdx.x >> 6);
    const int ws = gridDim.x * 4;
    const int items = jb.M >> 4;

    const u16* wbase = jb.WT1 + (size_t)c * K1 + kg * 8;
    s8v bp[KS1][8];
#pragma unroll
    for (int ks = 0; ks < KS1; ++ks)
#pragma unroll
        for (int nt = 0; nt < 8; ++nt)
            bp[ks][nt] = *(const s8v*)(wbase + ((size_t)nt * 16) * K1 + ks * 32);

    float bc0[8];
#pragma unroll
    for (int nt = 0; nt < 8; ++nt)
        bc0[nt] = bias0 ? bias0[nt * 16 + c] : 0.f;

    auto lda = [&](s8v* a, int item) {
        const u16* ap = A1 + (size_t)((item << 4) + c) * K1 + kg * 8;
#pragma unroll
        for (int ks = 0; ks < KS1; ++ks) a[ks] = *(const s8v*)(ap + ks * 32);
    };

    s8v a[KS1], an[KS1], a2[KS1];
    int item = wid;
    if (item < items) lda(a, item);
    if (item + ws < items) lda(an, item + ws);
    while (item < items) {
        const int i2 = item + 2 * ws;
        if (i2 < items) lda(a2, i2);

        f4v acc[8];
#pragma unroll
        for (int nt = 0; nt < 8; ++nt) acc[nt] = (f4v){0.f, 0.f, 0.f, 0.f};
#pragma unroll
        for (int ks = 0; ks < KS1; ++ks)
#pragma unroll
            for (int nt = 0; nt < 8; ++nt)
                acc[nt] = __builtin_amdgcn_mfma_f32_16x16x32_bf16(a[ks], bp[ks][nt], acc[nt], 0, 0, 0);

        const int r0 = item << 4;
#pragma unroll
        for (int nt = 0; nt < 8; ++nt)
#pragma unroll
            for (int j = 0; j < 4; ++j) {
                float v = acc[nt][j] + bc0[nt];
                if (RELU) v = fmaxf(v, 0.f);
                out[(size_t)(r0 + kg * 4 + j) * 128 + nt * 16 + c] = f2bf(v);
            }

#pragma unroll
        for (int ks = 0; ks < KS1; ++ks) { a[ks] = an[ks]; an[ks] = a2[ks]; }
        item += ws;
    }
}

// ---- fused head: sigmoid(relu(A@W1+b1) @ w2 + b2) -> [M,2] fp32 (r8) ----
__global__ __launch_bounds__(256) void head_fused(
    const u16* __restrict__ A1, const u16* __restrict__ WT,
    const float* __restrict__ b1, const float* __restrict__ w2,
    const float* __restrict__ b2, float* __restrict__ outp, int M)
{
    constexpr int KT = 128;
    const int lane = threadIdx.x & 63;
    const int c = lane & 15;
    const int kg = lane >> 4;
    const int wid = blockIdx.x * 4 + (threadIdx.x >> 6);
    const int ws = gridDim.x * 4;
    const int items = M >> 4;

    const u16* wbase = WT + (size_t)c * KT + kg * 8;
    s8v bp[4][8];
#pragma unroll
    for (int ks = 0; ks < 4; ++ks)
#pragma unroll
        for (int nt = 0; nt < 8; ++nt)
            bp[ks][nt] = *(const s8v*)(wbase + ((size_t)nt * 16) * KT + ks * 32);

    float bc[8], w2c0[8], w2c1[8];
#pragma unroll
    for (int nt = 0; nt < 8; ++nt) {
        int col = nt * 16 + c;
        bc[nt] = b1[col];
        w2c0[nt] = w2[col * 2 + 0];
        w2c1[nt] = w2[col * 2 + 1];
    }
    const float s0 = b2[0], s1 = b2[1];

    for (int item = wid; item < items; item += ws) {
        const int r0 = item << 4;
        const u16* ap = A1 + (size_t)(r0 + c) * 128 + kg * 8;
        s8v a[4];
#pragma unroll
        for (int ks = 0; ks < 4; ++ks) a[ks] = *(const s8v*)(ap + ks * 32);

        f4v acc[8];
#pragma unroll
        for (int nt = 0; nt < 8; ++nt) acc[nt] = (f4v){0.f, 0.f, 0.f, 0.f};
#pragma unroll
        for (int ks = 0; ks < 4; ++ks)
#pragma unroll
            for (int nt = 0; nt < 8; ++nt)
                acc[nt] = __builtin_amdgcn_mfma_f32_16x16x32_bf16(a[ks], bp[ks][nt], acc[nt], 0, 0, 0);

        float pp0[4] = {0.f, 0.f, 0.f, 0.f}, pp1[4] = {0.f, 0.f, 0.f, 0.f};
#pragma unroll
        for (int nt = 0; nt < 8; ++nt)
#pragma unroll
            for (int j = 0; j < 4; ++j) {
                float v = fmaxf(acc[nt][j] + bc[nt], 0.f);
                pp0[j] += v * w2c0[nt];
                pp1[j] += v * w2c1[nt];
            }
#pragma unroll
        for (int m = 1; m < 16; m <<= 1)
#pragma unroll
            for (int j = 0; j < 4; ++j) {
                pp0[j] += __shfl_xor(pp0[j], m);
                pp1[j] += __shfl_xor(pp1[j], m);
            }
        if (c == 0) {
#pragma unroll
            for (int j = 0; j < 4; ++j) {
                int row = r0 + kg * 4 + j;
                outp[(size_t)row * 2 + 0] = 1.f / (1.f + expf(-(pp0[j] + s0)));
                outp[(size_t)row * 2 + 1] = 1.f / (1.f + expf(-(pp1[j] + s1)));
            }
        }
    }
}

// ============================ CSR counting sort ============================
__global__ __launch_bounds__(256) void binA(
    const int* __restrict__ src, const int* __restrict__ dst,
    int E, int CH, int NB, int nbk_c, int NBK,
    int* __restrict__ G, int* __restrict__ Tb)
{
    __shared__ int h[1024];
    const int blk = blockIdx.x, tid = threadIdx.x;
    for (int i = tid; i < NBK; i += 256) h[i] = 0;
    __syncthreads();
    const int e0 = blk * CH, e1 = min(E, e0 + CH);
    for (int e = e0 + tid; e < e1; e += 256) {
        atomicAdd(&h[dst[e] >> 9], 1);
        atomicAdd(&h[nbk_c + (src[e] >> 9)], 1);
    }
    __syncthreads();
    for (int b = tid; b < NBK; b += 256) {
        const int v = h[b];
        G[b * NB + blk] = v;
        if (v) atomicAdd(&Tb[b], v);
    }
}

__global__ __launch_bounds__(512) void binS(
    const int* __restrict__ Tb, int NBK, int* __restrict__ BB)
{
    __shared__ int wsum[8];
    const int tid = threadIdx.x;
    const int T = (tid < NBK) ? Tb[tid] : 0;
    const int lane = tid & 63, wv = tid >> 6;
    int incl = T;
#pragma unroll
    for (int d = 1; d < 64; d <<= 1) {
        int up = __shfl_up(incl, d);
        if (lane >= d) incl += up;
    }
    if (lane == 63) wsum[wv] = incl;
    __syncthreads();
    if (tid == 0) {
        int run = 0;
        for (int w = 0; w < 8; ++w) { int t = wsum[w]; wsum[w] = run; run += t; }
    }
    __syncthreads();
    const int base = wsum[wv] + incl - T;
    if (tid < NBK) {
        BB[tid] = base;
        if (tid == NBK - 1) BB[NBK] = base + T;
    }
}

__global__ __launch_bounds__(64) void binP(
    const int* __restrict__ G, const int* __restrict__ BB,
    int NB, int* __restrict__ PBB)
{
    const int b = blockIdx.x, l = threadIdx.x;
    const int* g = G + (size_t)b * NB;
    const int v0 = (l < NB) ? g[l] : 0;
    const int v1 = (l + 64 < NB) ? g[l + 64] : 0;
    int i0 = v0, i1 = v1;
#pragma unroll
    for (int d = 1; d < 64; d <<= 1) {
        int u0 = __shfl_up(i0, d);
        int u1 = __shfl_up(i1, d);
        if (l >= d) { i0 += u0; i1 += u1; }
    }
    const int t0 = __shfl(i0, 63);
    const int base = BB[b];
    int* p = PBB + (size_t)b * NB;
    if (l < NB) p[l] = base + i0 - v0;
    if (l + 64 < NB) p[l + 64] = base + t0 + i1 - v1;
}

__global__ __launch_bounds__(256) void binB(
    const int* __restrict__ src, const int* __restrict__ dst,
    int E, int CH, int NB, int nbk_c, int NBK,
    const int* __restrict__ PBB, unsigned* __restrict__ REC)
{
    __shared__ int fill[1024];
    const int blk = blockIdx.x, tid = threadIdx.x;
    for (int i = tid; i < NBK; i += 256) fill[i] = 0;
    __syncthreads();
    const int e0 = blk * CH, e1 = min(E, e0 + CH);
    for (int e = e0 + tid; e < e1; e += 256) {
        const int s = src[e], d = dst[e];
        const int bc = d >> 9;
        const int pc = PBB[bc * NB + blk] + atomicAdd(&fill[bc], 1);
        REC[pc] = (unsigned)s | ((unsigned)(d & 511) << 17);
        const int bp = nbk_c + (s >> 9);
        const int pp = PBB[bp * NB + blk] + atomicAdd(&fill[bp], 1);
        REC[pp] = (unsigned)d | ((unsigned)(s & 511) << 17);
    }
}

__global__ __launch_bounds__(256) void binC2(
    const unsigned* __restrict__ REC, const int* __restrict__ BB,
    int nbk_c, int NCn, int NPn,
    int* __restrict__ off_c, int* __restrict__ cnt_c,
    int* __restrict__ off_p, int* __restrict__ cnt_p, int* __restrict__ AJ)
{
    __shared__ int nh[512], lo[512], fl[512], ws2[4];
    const int b = blockIdx.x, tid = threadIdx.x;
    int Nn, node0;
    int *off_out, *cnt_out;
    if (b < nbk_c) { Nn = NCn; node0 = b << 9; off_out = off_c; cnt_out = cnt_c; }
    else { Nn = NPn; node0 = (b - nbk_c) << 9; off_out = off_p; cnt_out = cnt_p; }
    const int r0 = BB[b], r1 = BB[b + 1];
    const int kmax = min(512, Nn - node0);
    nh[tid] = 0; nh[tid + 256] = 0;
    fl[tid] = 0; fl[tid + 256] = 0;
    __syncthreads();
    for (int i = r0 + tid; i < r1; i += 256)
        atomicAdd(&nh[REC[i] >> 17], 1);
    __syncthreads();
    const int v0 = nh[2 * tid], v1 = nh[2 * tid + 1];
    const int s = v0 + v1;
    const int lane = tid & 63, wv = tid >> 6;
    int incl = s;
#pragma unroll
    for (int d = 1; d < 64; d <<= 1) {
        int up = __shfl_up(incl, d);
        if (lane >= d) incl += up;
    }
    if (lane == 63) ws2[wv] = incl;
    __syncthreads();
    if (tid == 0) {
        int run = 0;
        for (int w = 0; w < 4; ++w) { int t = ws2[w]; ws2[w] = run; run += t; }
    }
    __syncthreads();
    const int base = ws2[wv] + incl - s;
    lo[2 * tid] = base;
    lo[2 * tid + 1] = base + v0;
    __syncthreads();
    for (int k = tid; k < kmax; k += 256) {
        off_out[node0 + k] = r0 + lo[k];
        cnt_out[node0 + k] = nh[k];
    }
    for (int i = r0 + tid; i < r1; i += 256) {
        const unsigned rec = REC[i];
        const int k = rec >> 17;
        const int pos = r0 + lo[k] + atomicAdd(&fl[k], 1);
        AJ[pos] = (int)(rec & 0x1FFFFu);
    }
}

// ---- gather: Sdiv[n] = mean_e relu((RW[n]+LW[adj])*sf) ----
__global__ __launch_bounds__(256) void node_gather2(
    const int* __restrict__ off, const int* __restrict__ cnt,
    const int* __restrict__ adj,
    const u16* __restrict__ RW, const u16* __restrict__ LW,
    u16* __restrict__ Sdiv, float* __restrict__ cntf,
    const float* __restrict__ sf_p, int N)
{
    int t = blockIdx.x * 256 + threadIdx.x;
    int n = t >> 5;
    if (n >= N) return;
    int l32 = t & 31;
    int c = l32 & 15;
    int half = l32 >> 4;
    const float sf = *sf_p;
    const int start = off[n], len = cnt[n];

    float rw[8];
    unpack8(*(const uint4*)(RW + (size_t)n * 128 + c * 8), rw);
    float acc[8] = {0.f, 0.f, 0.f, 0.f, 0.f, 0.f, 0.f, 0.f};

    for (int i = half; i < len; i += 2) {
        int l = adj[start + i];
        float lw[8];
        unpack8(*(const uint4*)(LW + (size_t)l * 128 + c * 8), lw);
#pragma unroll
        for (int j = 0; j < 8; ++j)
            acc[j] += fmaxf((rw[j] + lw[j]) * sf, 0.f);
    }
#pragma unroll
    for (int j = 0; j < 8; ++j) acc[j] += __shfl_xor(acc[j], 16);

    if (half == 0) {
        float inv = 1.f / fmaxf((float)len, 1.f);
        uint4 o;
        o.x = pk2(acc[0] * inv, acc[1] * inv);
        o.y = pk2(acc[2] * inv, acc[3] * inv);
        o.z = pk2(acc[4] * inv, acc[5] * inv);
        o.w = pk2(acc[6] * inv, acc[7] * inv);
        *(uint4*)(Sdiv + (size_t)n * 128 + c * 8) = o;
        if (l32 == 0) cntf[n] = (float)len;
    }
}

extern "C" void kernel_launch(void* const* d_in, const int* in_sizes, int n_in,
                              void* d_out, int out_size, void* d_ws, size_t ws_size,
                              hipStream_t stream)
{
    const float* pivot = (const float*)d_in[0];
    const float* child = (const float*)d_in[1];
    const int* edges = (const int*)d_in[2];
    const int F = in_sizes[3];           // 69
    const int NP = in_sizes[0] / F;
    const int NC = in_sizes[1] / F;
    const int E = in_sizes[2] / 2;
    const int* src = edges;
    const int* dst = edges + E;

    const float *pe_shift = (const float*)d_in[3], *pe_scale = (const float*)d_in[4],
                *pe_w1 = (const float*)d_in[5], *pe_b1 = (const float*)d_in[6],
                *pe_w2 = (const float*)d_in[7], *pe_b2 = (const float*)d_in[8];
    const float *ce_shift = (const float*)d_in[9], *ce_scale = (const float*)d_in[10],
                *ce_w1 = (const float*)d_in[11], *ce_b1 = (const float*)d_in[12],
                *ce_w2 = (const float*)d_in[13], *ce_b2 = (const float*)d_in[14];
    const float *vc_wl = (const float*)d_in[15], *vc_bl = (const float*)d_in[16],
                *vc_wr = (const float*)d_in[17], *vc_sf = (const float*)d_in[18],
                *vc_wf = (const float*)d_in[19], *vc_bf = (const float*)d_in[20],
                *vc_sp = (const float*)d_in[21], *vc_wo1 = (const float*)d_in[22],
                *vc_bo1 = (const float*)d_in[23], *vc_wo2 = (const float*)d_in[24],
                *vc_bo2 = (const float*)d_in[25];
    const float *cv_wl = (const float*)d_in[26], *cv_bl = (const float*)d_in[27],
                *cv_wr = (const float*)d_in[28], *cv_sf = (const float*)d_in[29],
                *cv_wf = (const float*)d_in[30], *cv_bf = (const float*)d_in[31],
                *cv_sp = (const float*)d_in[32], *cv_wo1 = (const float*)d_in[33],
                *cv_bo1 = (const float*)d_in[34], *cv_wo2 = (const float*)d_in[35],
                *cv_bo2 = (const float*)d_in[36];
    const float *out_w1 = (const float*)d_in[37], *out_b1 = (const float*)d_in[38],
                *out_w2 = (const float*)d_in[39], *out_b2 = (const float*)d_in[40];

    // ---- workspace carve (256B aligned) ----
    char* base = (char*)d_ws;
    size_t off = 0;
    auto carve = [&](size_t bytes) {
        void* p = base + off;
        off += (bytes + 255) & ~(size_t)255;
        return p;
    };
    float* Wsc = (float*)carve((size_t)4 * 16384 * 4);
    float* Vsc = (float*)carve((size_t)4 * 128 * 4);
    u16* WT = (u16*)carve((size_t)14 * 32768 * 2);
    u16* FPC = (u16*)carve((size_t)(NP + NC) * 96 * 2);
    u16* FP = FPC;
    u16* FC = FPC + (size_t)NP * 96;
    u16* B0 = (u16*)carve((size_t)NP * 128 * 2);   // pv0
    u16* B1 = (u16*)carve((size_t)NC * 128 * 2);
    u16* B2 = (u16*)carve((size_t)NC * 128 * 2);   // ch0
    u16* B3 = (u16*)carve((size_t)NC * 128 * 2);   // LW_v -> LW_c
    u16* B4 = (u16*)carve((size_t)NC * 128 * 2);   // Sdiv
    u16* B5 = (u16*)carve((size_t)NC * 128 * 2);   // embed temp / h_c
    u16* B6 = (u16*)carve((size_t)NP * 128 * 2);   // RW_p
    const int NMAX = (NC > NP) ? NC : NP;
    float* cntf = (float*)carve((size_t)NMAX * 4);

    const int NB = 120;
    const int CH = (E + NB - 1) / NB;
    const int nbk_c = (NC + 511) >> 9;
    const int nbk_p = (NP + 511) >> 9;
    const int NBK = nbk_c + nbk_p;
    int* cnt_c = (int*)carve((size_t)NC * 4);
    int* cnt_p = (int*)carve((size_t)NP * 4);
    int* off_c = (int*)carve((size_t)NC * 4);
    int* off_p = (int*)carve((size_t)NP * 4);
    int* G = (int*)carve((size_t)NBK * NB * 4);
    int* PBB = (int*)carve((size_t)NBK * NB * 4);
    int* BB = (int*)carve((size_t)(NBK + 1) * 4);
    int* Tb = (int*)carve((size_t)NBK * 4);
    unsigned* REC = (unsigned*)carve((size_t)2 * E * 4);
    int* AJ = (int*)carve((size_t)2 * E * 4);

    // ---- folded weight precompute (fp32) ----
    SmPack sp;
    sp.e[0] = {vc_wf, vc_wo1, vc_sp};
    sp.e[1] = {cv_wf, cv_wo1, cv_sp};
    sp.e[2] = {vc_wo2, cv_wr, nullptr};
    sp.e[3] = {cv_wo2, out_w1, nullptr};
    hipLaunchKernelGGL(smallmm, dim3(256), dim3(256), 0, stream, sp, Wsc);
    hipLaunchKernelGGL(vecpre, dim3(1), dim3(128), 0, stream,
                       vc_bf, vc_wo1, vc_sp, cv_bf, cv_wo1, cv_sp,
                       vc_bo2, cv_wr, cv_bo2, out_w1, out_b1, Vsc);
    const float* cvec_vc = Vsc;
    const float* cvec_cv = Vsc + 128;
    const float* cx = Vsc + 256;
    const float* bh = Vsc + 384;

    // ---- weight conversion ----
    WPack wp;
    auto setw = [&](int i, const float* s, int ks, int kd) {
        wp.e[i].src = s; wp.e[i].Ksrc = ks; wp.e[i].Kdst = kd;
    };
    setw(0, pe_w1, F, 96);            setw(1, pe_w2, 128, 128);
    setw(2, ce_w1, F, 96);            setw(3, ce_w2, 128, 128);
    setw(4, vc_wl, 128, 128);         setw(5, vc_wr, 128, 128);
    setw(6, Wsc + 0 * 16384, 128, 128);
    setw(7, vc_wo1 + 128 * 128, 128, 128);
    setw(8, Wsc + 2 * 16384, 128, 128);
    setw(9, cv_wl, 128, 128);         setw(10, cv_wr, 128, 128);
    setw(11, Wsc + 1 * 16384, 128, 128);
    setw(12, cv_wo1 + 128 * 128, 128, 128);
    setw(13, Wsc + 3 * 16384, 128, 128);
    hipLaunchKernelGGL(wconvert, dim3(14 * 128), dim3(256), 0, stream, wp, WT);
    auto wt = [&](int i) { return WT + (size_t)i * 32768; };

    // ---- feature conversion (both tables, one dispatch) ----
    hipLaunchKernelGGL(featconv2, dim3(2048), dim3(256), 0, stream,
                       pivot, child, pe_shift, pe_scale, ce_shift, ce_scale,
                       FPC, (long)NP, (long)(NP + NC) * 96, F);

    // ---- CSR via counting sort ----
    hipMemsetAsync(Tb, 0, (size_t)NBK * 4, stream);
    hipLaunchKernelGGL(binA, dim3(NB), dim3(256), 0, stream,
                       src, dst, E, CH, NB, nbk_c, NBK, G, Tb);
    hipLaunchKernelGGL(binS, dim3(1), dim3(512), 0, stream, Tb, NBK, BB);
    hipLaunchKernelGGL(binP, dim3(NBK), dim3(64), 0, stream, G, BB, NB, PBB);
    hipLaunchKernelGGL(binB, dim3(NB), dim3(256), 0, stream,
                       src, dst, E, CH, NB, nbk_c, NBK, PBB, REC);
    hipLaunchKernelGGL(binC2, dim3(NBK), dim3(256), 0, stream,
                       REC, BB, nbk_c, NC, NP, off_c, cnt_c, off_p, cnt_p, AJ);

    // ---- GEMM pipeline ----
    const dim3 blk(256);
    auto grd = [](int M) {
        int items = M >> 4;
        int b = (items + 3) / 4;
        return dim3((unsigned)(b < 512 ? b : 512));
    };

    // embeddings layer 1 (batched): FP->B1 (NP), FC->B5 (NC)
    {
        GJobs3 j;
        j.j[0] = {FP, wt(0), pe_b1, B1, NP};
        j.j[1] = {FC, wt(2), ce_b1, B5, NC};
        j.j[2] = j.j[0];
        dim3 g = grd(NC); g.y = 2;
        hipLaunchKernelGGL(HIP_KERNEL_NAME(gemm_multi<3, true>), g, blk, 0, stream, j);
    }
    // embeddings layer 2 (batched): B1->B0 (pv0), B5->B2 (ch0)
    {
        GJobs3 j;
        j.j[0] = {B1, wt(1), pe_b2, B0, NP};
        j.j[1] = {B5, wt(3), ce_b2, B2, NC};
        j.j[2] = j.j[0];
        dim3 g = grd(NC); g.y = 2;
        hipLaunchKernelGGL(HIP_KERNEL_NAME(gemm_multi<4, true>), g, blk, 0, stream, j);
    }
    // RW_c / LW_v / RW_p (batched)
    {
        GJobs3 j;
        j.j[0] = {B2, wt(4), vc_bl, B1, NC};    // RW_c = ch0@wl+bl
        j.j[1] = {B0, wt(5), nullptr, B3, NP};  // LW_v = pv0@wr
        j.j[2] = {B0, wt(9), cv_bl, B6, NP};    // RW_p = pv0@cv_wl+bl
        dim3 g = grd(NC); g.y = 3;
        hipLaunchKernelGGL(HIP_KERNEL_NAME(gemm_multi<4, false>), g, blk, 0, stream, j);
    }

    // conv v->c
    hipLaunchKernelGGL(node_gather2, dim3(((size_t)NC * 32 + 255) / 256), blk, 0,
                       stream, off_c, cnt_c, AJ, B1, B3, B4, cntf, vc_sf, NC);
    gemm_rb<4, true, true, true><<<grd(NC), blk, 0, stream>>>(
        B4, B2, wt(6), wt(7), vc_bo1, cvec_vc, cntf, B5, NC);            // h_c
    gemm_rb<4, false, false, false><<<grd(NC), blk, 0, stream>>>(
        B5, nullptr, wt(8), nullptr, cx, nullptr, nullptr, B3, NC);      // LW_c

    // conv c->v
    hipLaunchKernelGGL(node_gather2, dim3(((size_t)NP * 32 + 255) / 256), blk, 0,
                       stream, off_p, cnt_p, AJ, B6, B3, B4, cntf, cv_sf, NP);
    gemm_rb<4, true, true, true><<<grd(NP), blk, 0, stream>>>(
        B4, B0, wt(11), wt(12), cv_bo1, cvec_cv, cntf, B1, NP);          // h_p

    // head on h_p with folded W1'=Wh, b1'=bh
    hipLaunchKernelGGL(head_fused, grd(NP), blk, 0, stream,
                       B1, wt(13), bh, out_w2, out_b2, (float*)d_out, NP);
}